// Round 1
// baseline (222.356 us; speedup 1.0000x reference)
//
#include <hip/hip_runtime.h>
#include <hip/hip_bf16.h>
#include <math.h>

#define PI_D 3.14159265358979323846
#define NLAT 128
#define NLON 256
#define LMAX 50
#define MMAX 50
#define NPTS 2048
#define NFIELD 4   // {pred,target} x {b0,b1}
#define MGRID (NLAT * NLON)

// ---------------------------------------------------------------------------
// Kernel A: Legendre * quadrature-weight table PCTW[m][l][k], double precision
// to match numpy float64 -> float32 cast. grid: 50 blocks (m), 128 threads (k).
// ---------------------------------------------------------------------------
__global__ void precompute_pctw(float* __restrict__ pctw) {
    int k = threadIdx.x;   // 0..127 (latitude node)
    int m = blockIdx.x;    // 0..49
    double theta = PI_D * (double)k / 127.0;
    double cost = cos(theta);
    double sint = sqrt(fmax(1.0 - cost * cost, 0.0));

    // Clenshaw-Curtis weight (Nn = 127, all b = 2.0 since 127 is odd)
    double v = 0.0;
    for (int t = 1; t <= 63; ++t)
        v += 2.0 * cos(2.0 * (double)t * theta) / (4.0 * (double)t * (double)t - 1.0);
    double w = (2.0 / 127.0) * (1.0 - v);
    if (k == 0 || k == 127) w *= 0.5;

    // pmm recurrence up to order m
    double pmm = sqrt(1.0 / (4.0 * PI_D));
    for (int i = 1; i <= m; ++i)
        pmm = -pmm * sqrt((2.0 * (double)i + 1.0) / (2.0 * (double)i)) * sint;

    float* out = pctw + (m * LMAX) * NLAT + k;  // [m][l][k], stride NLAT per l
    for (int l = 0; l < m; ++l) out[l * NLAT] = 0.0f;

    out[m * NLAT] = (float)(pmm * w);
    double plm2 = pmm, plm1 = 0.0;
    if (m + 1 < LMAX) {
        plm1 = sqrt(2.0 * (double)m + 3.0) * cost * pmm;
        out[(m + 1) * NLAT] = (float)(plm1 * w);
    }
    for (int l = m + 2; l < LMAX; ++l) {
        double ll = (double)l;
        double denom = ll * ll - (double)(m * m);
        double a = sqrt((4.0 * ll * ll - 1.0) / denom);
        double b = sqrt(((2.0 * ll + 1.0) * (double)(l - 1 + m) * (double)(l - 1 - m)) /
                        ((2.0 * ll - 3.0) * denom));
        double p = a * cost * plm1 - b * plm2;
        out[l * NLAT] = (float)(p * w);
        plm2 = plm1;
        plm1 = p;
    }
}

// ---------------------------------------------------------------------------
// Kernel B: to_spherical for all 4 fields. sph[f][n] = (theta, az-pi, r, pad)
// ---------------------------------------------------------------------------
__global__ void to_sph(const float* __restrict__ pred, const float* __restrict__ tgt,
                       float* __restrict__ sph) {
    int idx = blockIdx.x * blockDim.x + threadIdx.x;  // 0..8191
    if (idx >= NFIELD * NPTS) return;
    int f = idx >> 11;   // 0..3
    int n = idx & (NPTS - 1);
    const float* src = ((f < 2) ? pred : tgt) + ((size_t)(f & 1) * NPTS + n) * 3;
    float x = src[0], y = src[1], z = src[2];
    // match reference summation order: flip-cumsum-flip
    float s1 = z * z;
    float s2 = s1 + y * y;
    float s3 = s2 + x * x;
    float r = sqrtf(s3);
    float rho = sqrtf(s2);
    float theta = acosf(x / r);
    float a = acosf(y / rho);
    float az = (z < 0.0f) ? (a + (2.0f * (float)PI_D - 2.0f * a)) : a;
    az -= (float)PI_D;
    float4* dst = (float4*)(sph + (size_t)idx * 4);
    *dst = make_float4(theta, az, r, 0.0f);
}

// ---------------------------------------------------------------------------
// Kernel C: brute-force 3-NN + distance-weighted interp onto the grid.
// grid: (MGRID/256, NFIELD) blocks, 256 threads. Points staged in LDS.
// ---------------------------------------------------------------------------
__global__ __launch_bounds__(256) void knn_interp(const float* __restrict__ sph,
                                                  float* __restrict__ gridf) {
    __shared__ float s_t[NPTS], s_l[NPTS], s_r[NPTS];
    int f = blockIdx.y;
    const float4* base = (const float4*)(sph + (size_t)f * NPTS * 4);
    for (int n = threadIdx.x; n < NPTS; n += 256) {
        float4 p = base[n];
        s_t[n] = p.x;
        s_l[n] = p.y;
        s_r[n] = p.z;
    }
    __syncthreads();

    int m = blockIdx.x * 256 + threadIdx.x;  // 0..32767
    int i = m >> 8;        // lat index
    int j = m & 255;       // lon index
    float gt = (float)((double)i * PI_D / 128.0);
    float gl = (float)(((double)j - 128.0) * PI_D / 128.0);

    float d0 = 1e30f, d1 = 1e30f, d2 = 1e30f;
    float r0 = 0.0f, r1 = 0.0f, r2 = 0.0f;
#pragma unroll 4
    for (int n = 0; n < NPTS; ++n) {
        float dt = gt - s_t[n];
        float dl = gl - s_l[n];
        float d = dt * dt + dl * dl;
        float rr = s_r[n];
        bool c0 = d < d0, c1 = d < d1, c2 = d < d2;
        // branchless sorted-insert into (d0 <= d1 <= d2)
        float nd2 = c1 ? d1 : (c2 ? d : d2);
        float nr2 = c1 ? r1 : (c2 ? rr : r2);
        float nd1 = c0 ? d0 : (c1 ? d : d1);
        float nr1 = c0 ? r0 : (c1 ? rr : r1);
        float nd0 = c0 ? d : d0;
        float nr0 = c0 ? rr : r0;
        d0 = nd0; d1 = nd1; d2 = nd2;
        r0 = nr0; r1 = nr1; r2 = nr2;
    }
    // weights = d_k / sum(d_k)  (as in the source: farther neighbor weighs MORE)
    float s = d0 + d1 + d2;
    gridf[(size_t)f * MGRID + m] = (d0 * r0 + d1 * r1 + d2 * r2) / s;
}

// ---------------------------------------------------------------------------
// Kernel D: real part of rfft * (2*pi/NLON), first MMAX modes.
// fre[f][k][mm] ; one thread per (f,k,mm).
// ---------------------------------------------------------------------------
__global__ __launch_bounds__(256) void dft_cos(const float* __restrict__ gridf,
                                               float* __restrict__ fre) {
    __shared__ float ctab[NLON];
    int t = threadIdx.x;
    ctab[t] = (float)cos(2.0 * PI_D * (double)t / (double)NLON);
    __syncthreads();

    int idx = blockIdx.x * 256 + t;  // f*128*50 + k*50 + mm
    if (idx >= NFIELD * NLAT * MMAX) return;
    int mm = idx % MMAX;
    int fk = idx / MMAX;  // f*NLAT + k
    const float* row = gridf + (size_t)fk * NLON;
    float acc = 0.0f;
    int p = 0;
    for (int j = 0; j < NLON; ++j) {
        acc += row[j] * ctab[p];
        p += mm;
        p &= (NLON - 1);
    }
    fre[idx] = acc * (float)(2.0 * PI_D / (double)NLON);
}

// ---------------------------------------------------------------------------
// Kernel E: Legendre contraction + squared-diff loss with RECTW weighting.
// one thread per (b,l,mm); wave-reduce then atomicAdd into d_out.
// ---------------------------------------------------------------------------
__global__ __launch_bounds__(256) void contract_loss(const float* __restrict__ fre,
                                                     const float* __restrict__ pctw,
                                                     float* __restrict__ out) {
    int idx = blockIdx.x * 256 + threadIdx.x;  // b*2500 + l*50 + mm
    float contrib = 0.0f;
    if (idx < 2 * LMAX * MMAX) {
        int b = idx / (LMAX * MMAX);
        int lm = idx % (LMAX * MMAX);
        int l = lm / MMAX;
        int mm = lm % MMAX;
        const float* pw = pctw + (size_t)(mm * LMAX + l) * NLAT;
        const float* fp = fre + (size_t)(0 * 2 + b) * NLAT * MMAX + mm;  // stride MMAX over k
        const float* ft = fre + (size_t)(2 + b) * NLAT * MMAX + mm;
        float pc = 0.0f, tc = 0.0f;
#pragma unroll 4
        for (int k = 0; k < NLAT; ++k) {
            float w = pw[k];
            pc += fp[k * MMAX] * w;
            tc += ft[k * MMAX] * w;
        }
        float diff = pc - tc;
        double dl = (double)(49 - l);
        float rw = (float)exp(-(dl * dl) / 5000.0);
        contrib = diff * diff * rw * 0.5f;  // 0.5 = mean over batch of 2
    }
    for (int off = 32; off > 0; off >>= 1) contrib += __shfl_down(contrib, off);
    if ((threadIdx.x & 63) == 0) atomicAdd(out, contrib);
}

// ---------------------------------------------------------------------------
extern "C" void kernel_launch(void* const* d_in, const int* in_sizes, int n_in,
                              void* d_out, int out_size, void* d_ws, size_t ws_size,
                              hipStream_t stream) {
    const float* pred = (const float*)d_in[0];
    const float* tgt = (const float*)d_in[1];
    float* ws = (float*)d_ws;

    // ws layout (floats):
    float* pctw  = ws;                       // 50*50*128        = 320000
    float* sph   = ws + 320000;              // 4*2048*4         =  32768
    float* gridf = ws + 320000 + 32768;      // 4*32768          = 131072
    float* fre   = ws + 320000 + 32768 + 131072;  // 4*128*50    =  25600
    float* out = (float*)d_out;

    hipMemsetAsync(out, 0, sizeof(float), stream);

    precompute_pctw<<<LMAX, NLAT, 0, stream>>>(pctw);
    to_sph<<<(NFIELD * NPTS + 255) / 256, 256, 0, stream>>>(pred, tgt, sph);
    knn_interp<<<dim3(MGRID / 256, NFIELD), 256, 0, stream>>>(sph, gridf);
    dft_cos<<<(NFIELD * NLAT * MMAX + 255) / 256, 256, 0, stream>>>(gridf, fre);
    contract_loss<<<(2 * LMAX * MMAX + 255) / 256, 256, 0, stream>>>(fre, pctw, out);
}